// Round 6
// baseline (244.678 us; speedup 1.0000x reference)
//
#include <hip/hip_runtime.h>
#include <hip/hip_bf16.h>

typedef unsigned short u16;
typedef unsigned long long u64;
typedef float f32x4 __attribute__((ext_vector_type(4)));
typedef __bf16 bf16x8 __attribute__((ext_vector_type(8)));

#define NB 2
#define NS 2048
#define ND 1024
#define NH 16
#define HD 64

__device__ inline u16 bfbits(float f) { __bf16 h = (__bf16)f; return __builtin_bit_cast(u16, h); }

__device__ inline void gl16(const u16* g, u16* l) {
  __builtin_amdgcn_global_load_lds((const __attribute__((address_space(1))) void*)(g),
                                   (__attribute__((address_space(3))) void*)(l), 16, 0, 0);
}

// ---------------- prep kernels ----------------

// transpose W [K][N] f32 -> WT [N][K] bf16 bits; blockIdx.z selects which weight
__global__ void __launch_bounds__(256)
prep_weight4(const float* __restrict__ W0, const float* __restrict__ W1,
             const float* __restrict__ W2, const float* __restrict__ W3,
             u16* __restrict__ T0, u16* __restrict__ T1, u16* __restrict__ T2, u16* __restrict__ T3) {
  __shared__ float tile[32][33];
  const float* Ws[4] = {W0, W1, W2, W3};
  u16* Ts[4] = {T0, T1, T2, T3};
  const float* __restrict__ W = Ws[blockIdx.z];
  u16* __restrict__ WT = Ts[blockIdx.z];
  const int tx = threadIdx.x, ty = threadIdx.y;
  const int n0 = blockIdx.x * 32, k0 = blockIdx.y * 32;
#pragma unroll
  for (int i = 0; i < 4; ++i)
    tile[ty + i * 8][tx] = W[(size_t)(k0 + ty + i * 8) * ND + n0 + tx];
  __syncthreads();
#pragma unroll
  for (int i = 0; i < 4; ++i)
    WT[(size_t)(n0 + ty + i * 8) * ND + k0 + tx] = bfbits(tile[tx][ty + i * 8]);
}

__global__ void __launch_bounds__(256)
convert_x(const float* __restrict__ x, u16* __restrict__ xb) {
  const int i = blockIdx.x * 256 + threadIdx.x;  // over NB*NS*ND/4
  float4 v = reinterpret_cast<const float4*>(x)[i];
  uint2 pk;
  pk.x = (unsigned)bfbits(v.x) | ((unsigned)bfbits(v.y) << 16);
  pk.y = (unsigned)bfbits(v.z) | ((unsigned)bfbits(v.w) << 16);
  reinterpret_cast<uint2*>(xb)[i] = pk;
}

__global__ void __launch_bounds__(256)
rope_tables(float* __restrict__ cost, float* __restrict__ sint) {
  const int i = blockIdx.x * 256 + threadIdx.x;  // NS*32
  const int s = i >> 5, d = i & 31;
  float invf = powf(10000.f, -(float)d / 32.f);
  float a = (float)s * invf;
  cost[i] = cosf(a);
  sint[i] = sinf(a);
}

// visibility bitmask: mb[(b*NS+q)*32 + kt] bit l = vis(q, kt*64+l). one wave per q-row.
// attn uses 128-row q-tiles; fill through the tile's end (ktmax = (q>>7)*2 + 1); entries past
// the row's own causal extent are correct zeros (ballot evaluates k > q -> vis=false).
__global__ void __launch_bounds__(256)
build_mask(const int* __restrict__ bar, const int* __restrict__ inst,
           const int* __restrict__ lidx, u64* __restrict__ mb) {
  const int w = threadIdx.x >> 6, lane = threadIdx.x & 63;
  const int pair = blockIdx.x * 4 + w;
  const int b = pair >> 11, q = pair & (NS - 1);
  const bool fc = (lidx[0] < 4);
  const int qb = bar[b * NS + q], qi = inst[b * NS + q];
  const int ktmax = ((q >> 7) << 1) + 1;  // cover the full 128-row q-tile's key range
  for (int kt = 0; kt <= ktmax; ++kt) {
    const int k = (kt << 6) + lane;
    const int kbv = bar[b * NS + k], kiv = inst[b * NS + k];
    bool vis;
    if (k > q) {
      vis = false;
    } else if (!fc) {
      vis = true;
    } else {
      const bool kreal = kiv < 129, qreal = qi < 129;
      int off = kbv - qb;
      off = off < -64 ? -64 : (off > 64 ? 64 : off);
      const bool rule = (kiv == qi) ? (off >= 0) : ((off >= 0 && off <= 2) || off == 4);
      vis = (kreal && qreal && rule) || (kiv == 129) || (kbv == -1);
    }
    const u64 wd = __ballot(vis);
    if (lane == 0) mb[(((size_t)b * NS + q) << 5) + kt] = wd;
  }
}

// ---------------- fused QKV GEMM ----------------
// A [4096][1024] bf16, BT3 [3072][1024] bf16 (WqT|WkT|WvT contiguous).
// grid (24, 32): blockIdx.x>>3 = projection (0:q rope, 1:k rope, 2:v transpose).
// 768 blocks = 3/CU; double-buffered LDS, 1 barrier per K-step (loads overlap MFMA).
__global__ void __launch_bounds__(256)
gemm_qkv(const u16* __restrict__ A, const u16* __restrict__ BT3,
         const float* __restrict__ bq, const float* __restrict__ bk, const float* __restrict__ bv,
         u16* __restrict__ qbuf, u16* __restrict__ kbuf, u16* __restrict__ vtbuf,
         const float* __restrict__ cost, const float* __restrict__ sint) {
  constexpr int K = ND;
  __shared__ alignas(16) u16 Alds[2][128][32];
  __shared__ alignas(16) u16 Blds[2][128][32];
  const int t = threadIdx.x;
  const int bx = blockIdx.x;
  const int proj = bx >> 3;
  const int n0 = (bx & 7) * 128;
  const int m0 = blockIdx.y * 128;
  const int w = t >> 6, lane = t & 63, lr = lane & 15, lg = lane >> 4;
  const int wr = w >> 1, wc = w & 1;
  const float* __restrict__ bias = proj == 0 ? bq : (proj == 1 ? bk : bv);
  f32x4 acc[4][4] = {};

  const int srow = lane >> 2;       // 0..15
  const int scol = (lane & 3) * 8;  // u16 offset
  const u16* Ag = A + (size_t)(m0 + w * 32 + srow) * K + scol;
  const u16* Bg = BT3 + (size_t)(proj * ND + n0 + w * 32 + srow) * K + scol;

  // prologue: stage k0=0 into buf 0
  gl16(Ag, &Alds[0][w * 32][0]);
  gl16(Ag + 16 * K, &Alds[0][w * 32 + 16][0]);
  gl16(Bg, &Blds[0][w * 32][0]);
  gl16(Bg + 16 * K, &Blds[0][w * 32 + 16][0]);

  int cur = 0;
  for (int k0 = 0; k0 < K; k0 += 32) {
    __syncthreads();  // buf[cur] staged (vmcnt drained); buf[cur^1] free
    if (k0 + 32 < K) {
      gl16(Ag + k0 + 32, &Alds[cur ^ 1][w * 32][0]);
      gl16(Ag + k0 + 32 + 16 * K, &Alds[cur ^ 1][w * 32 + 16][0]);
      gl16(Bg + k0 + 32, &Blds[cur ^ 1][w * 32][0]);
      gl16(Bg + k0 + 32 + 16 * K, &Blds[cur ^ 1][w * 32 + 16][0]);
    }
    bf16x8 af[4], bfr[4];
#pragma unroll
    for (int i = 0; i < 4; ++i)
      af[i] = *reinterpret_cast<const bf16x8*>(&Alds[cur][wr * 64 + i * 16 + lr][lg * 8]);
#pragma unroll
    for (int i = 0; i < 4; ++i)
      bfr[i] = *reinterpret_cast<const bf16x8*>(&Blds[cur][wc * 64 + i * 16 + lr][lg * 8]);
#pragma unroll
    for (int mi = 0; mi < 4; ++mi)
#pragma unroll
      for (int ni = 0; ni < 4; ++ni)
        acc[mi][ni] = __builtin_amdgcn_mfma_f32_16x16x32_bf16(af[mi], bfr[ni], acc[mi][ni], 0, 0, 0);
    cur ^= 1;
  }

  if (proj < 2) {
    u16* out = proj ? kbuf : qbuf;
    const int colbase = n0 + wc * 64;
    const int h = colbase >> 6;  // wave's 64 cols = one head
#pragma unroll
    for (int mi = 0; mi < 4; ++mi)
#pragma unroll
      for (int r = 0; r < 4; ++r) {
        const int row = m0 + wr * 64 + mi * 16 + lg * 4 + r;
        const int b = row >> 11, s = row & (NS - 1);
        u16* op = out + ((size_t)(b * NH + h) * NS + s) * HD;
#pragma unroll
        for (int nf = 0; nf < 2; ++nf) {
          const int dlo = nf * 16 + lr;  // < 32
          float lo = acc[mi][nf][r] + bias[colbase + dlo];
          float hi = acc[mi][nf + 2][r] + bias[colbase + dlo + 32];
          float c = cost[s * 32 + dlo], si = sint[s * 32 + dlo];
          op[dlo] = bfbits(lo * c - hi * si);
          op[dlo + 32] = bfbits(hi * c + lo * si);
        }
      }
  } else {
    u16* out = vtbuf;
#pragma unroll
    for (int mi = 0; mi < 4; ++mi)
#pragma unroll
      for (int r = 0; r < 4; ++r) {
        const int row = m0 + wr * 64 + mi * 16 + lg * 4 + r;
        const int b = row >> 11, s = row & (NS - 1);
#pragma unroll
        for (int ni = 0; ni < 4; ++ni) {
          const int col = n0 + wc * 64 + ni * 16 + lr;
          const int h = col >> 6, d = col & 63;
          out[((size_t)(b * NH + h) * HD + d) * NS + s] = bfbits(acc[mi][ni][r] + bias[col]);
        }
      }
  }
}

// ---------------- output GEMM (C = A*B^T + bias, f32 out), BM=128 BN=64 ----------------
// grid (16, 32) = 512 blocks = 2/CU. 4 row-waves, each 32 rows x 64 cols. dbuf, 1 barrier/K-step.
__global__ void __launch_bounds__(256)
gemm_out(const u16* __restrict__ A, const u16* __restrict__ BT, const float* __restrict__ bias,
         float* __restrict__ out) {
  constexpr int K = ND;
  __shared__ alignas(16) u16 Alds[2][128][32];
  __shared__ alignas(16) u16 Blds[2][64][32];
  const int t = threadIdx.x;
  const int n0 = blockIdx.x * 64;
  const int m0 = blockIdx.y * 128;
  const int w = t >> 6, lane = t & 63, lr = lane & 15, lg = lane >> 4;
  f32x4 acc[2][4] = {};

  const int srow = lane >> 2;
  const int scol = (lane & 3) * 8;
  const u16* Ag = A + (size_t)(m0 + w * 32 + srow) * K + scol;
  const u16* Bg = BT + (size_t)(n0 + w * 16 + srow) * K + scol;

  gl16(Ag, &Alds[0][w * 32][0]);
  gl16(Ag + 16 * K, &Alds[0][w * 32 + 16][0]);
  gl16(Bg, &Blds[0][w * 16][0]);

  int cur = 0;
  for (int k0 = 0; k0 < K; k0 += 32) {
    __syncthreads();
    if (k0 + 32 < K) {
      gl16(Ag + k0 + 32, &Alds[cur ^ 1][w * 32][0]);
      gl16(Ag + k0 + 32 + 16 * K, &Alds[cur ^ 1][w * 32 + 16][0]);
      gl16(Bg + k0 + 32, &Blds[cur ^ 1][w * 16][0]);
    }
    bf16x8 af[2], bfr[4];
#pragma unroll
    for (int i = 0; i < 2; ++i)
      af[i] = *reinterpret_cast<const bf16x8*>(&Alds[cur][w * 32 + i * 16 + lr][lg * 8]);
#pragma unroll
    for (int i = 0; i < 4; ++i)
      bfr[i] = *reinterpret_cast<const bf16x8*>(&Blds[cur][i * 16 + lr][lg * 8]);
#pragma unroll
    for (int mi = 0; mi < 2; ++mi)
#pragma unroll
      for (int ni = 0; ni < 4; ++ni)
        acc[mi][ni] = __builtin_amdgcn_mfma_f32_16x16x32_bf16(af[mi], bfr[ni], acc[mi][ni], 0, 0, 0);
    cur ^= 1;
  }

#pragma unroll
  for (int mi = 0; mi < 2; ++mi)
#pragma unroll
    for (int r = 0; r < 4; ++r) {
      const int row = m0 + w * 32 + mi * 16 + lg * 4 + r;
#pragma unroll
      for (int ni = 0; ni < 4; ++ni) {
        const int col = n0 + ni * 16 + lr;
        out[(size_t)row * ND + col] = acc[mi][ni][r] + bias[col];
      }
    }
}

// ---------------- fused masked flash attention (v5: barrier-free, K/V direct from global) ----
// grid (16, NH, NB) = 512 blocks x 8 waves. Wave w owns q-rows qbase+w*16+lr; K/V fragments are
// loaded straight global->VGPR (natural layout). The 16KB K+V tile is shared by the block's 8
// waves through L1 (32KB/CU) — no LDS staging, no __syncthreads, no vmcnt drain. Plds is
// per-wave (P transpose), needs no barrier. qt = b ? bx : 15-bx keeps co-resident blocks
// complementary in cost.
__global__ void __launch_bounds__(512, 4)
attn_fused(const u16* __restrict__ qb, const u16* __restrict__ kb, const u16* __restrict__ vtb,
           const u64* __restrict__ mb, u16* __restrict__ attnout) {
  __shared__ alignas(16) u16 Plds[8][16][64];   // per-wave P [q][k], swizzled 8B units
  const int t = threadIdx.x, w = t >> 6, lane = t & 63, lr = lane & 15, lg = lane >> 4;
  const int h = blockIdx.y, b = blockIdx.z;
  const int qt = b ? (int)blockIdx.x : 15 - (int)blockIdx.x;  // complementary pairs per CU
  const int qbase = qt * 128;
  const u16* __restrict__ qh = qb + (size_t)(b * NH + h) * NS * HD;
  const u16* __restrict__ kh = kb + (size_t)(b * NH + h) * NS * HD;
  const u16* __restrict__ vth = vtb + (size_t)(b * NH + h) * HD * NS;

  // Q fragments (B-operand of swapped QK^T): rows q = qbase + w*16 + lr
  const int qrow = qbase + w * 16 + lr;
  const bf16x8 qf0 = *reinterpret_cast<const bf16x8*>(qh + (size_t)qrow * HD + lg * 8);
  const bf16x8 qf1 = *reinterpret_cast<const bf16x8*>(qh + (size_t)qrow * HD + 32 + lg * 8);
  const u64* __restrict__ mrow = mb + (((size_t)b * NS + qrow) << 5);

  // per-lane invariant fragment bases: K row (n*16+lr) cols lg*8 / 32+lg*8; V^T row (nd*16+lr)
  const u16* __restrict__ kput = kh + lr * HD + lg * 8;
  const u16* __restrict__ vput = vth + (size_t)lr * NS + lg * 8;

  float m_s = -1e30f, l_s = 0.f;
  f32x4 oacc[4] = {};
  const int nt = 2 * qt + 2;  // causal: keys < qbase+128
  u64 mw = mrow[0];

  for (int kt = 0; kt < nt; ++kt) {
    const int kb0 = kt * 64;

    // S^T = K * Q^T : sacc[n][r] = S[q = qrow][k = kb0 + n*16 + lg*4 + r]
    const u16* kp = kput + (size_t)kb0 * HD;
    f32x4 sacc[4] = {};
    __builtin_amdgcn_s_setprio(1);
#pragma unroll
    for (int n = 0; n < 4; ++n) {
      bf16x8 kf0 = *reinterpret_cast<const bf16x8*>(kp + n * 16 * HD);
      bf16x8 kf1 = *reinterpret_cast<const bf16x8*>(kp + n * 16 * HD + 32);
      sacc[n] = __builtin_amdgcn_mfma_f32_16x16x32_bf16(kf0, qf0, sacc[n], 0, 0, 0);
      sacc[n] = __builtin_amdgcn_mfma_f32_16x16x32_bf16(kf1, qf1, sacc[n], 0, 0, 0);
    }
    __builtin_amdgcn_s_setprio(0);

    const u64 mwn = (kt + 1 < nt) ? mrow[kt + 1] : 0ULL;

    // mask (bit test) + row max. masked -> -3e30 so exp underflows even vs m = -1e30.
    float pm[4][4];
    float mx = -1e30f;
#pragma unroll
    for (int n = 0; n < 4; ++n)
#pragma unroll
      for (int r = 0; r < 4; ++r) {
        const bool vis = (mw >> (n * 16 + lg * 4 + r)) & 1ULL;
        const float sc = sacc[n][r] * 0.125f;
        pm[n][r] = vis ? sc : -3e30f;
        mx = fmaxf(mx, pm[n][r]);
      }
    mx = fmaxf(mx, __shfl_xor(mx, 16));
    mx = fmaxf(mx, __shfl_xor(mx, 32));
    const float mn = fmaxf(m_s, mx);
    const float sf = __expf(m_s - mn);
    m_s = mn;

    // exp + pack P to per-wave Plds (row q=lr, 4 consecutive k per b64 write, swizzled)
    float rs = 0.f;
#pragma unroll
    for (int n = 0; n < 4; ++n) {
      const float e0 = __expf(pm[n][0] - mn);
      const float e1 = __expf(pm[n][1] - mn);
      const float e2 = __expf(pm[n][2] - mn);
      const float e3 = __expf(pm[n][3] - mn);
      rs += (e0 + e1) + (e2 + e3);
      uint2 pk;
      pk.x = (unsigned)bfbits(e0) | ((unsigned)bfbits(e1) << 16);
      pk.y = (unsigned)bfbits(e2) | ((unsigned)bfbits(e3) << 16);
      *reinterpret_cast<uint2*>(&Plds[w][lr][(((n << 2) + lg) ^ (lr & 14)) << 2]) = pk;
    }
    rs += __shfl_xor(rs, 16);
    rs += __shfl_xor(rs, 32);
    l_s = l_s * sf + rs;

    // broadcast row-scale to oacc layout (rows = lg*4+r) and rescale
    float sfr[4];
#pragma unroll
    for (int r = 0; r < 4; ++r) sfr[r] = __shfl(sf, lg * 4 + r);
#pragma unroll
    for (int nd = 0; nd < 4; ++nd)
#pragma unroll
      for (int r = 0; r < 4; ++r) oacc[nd][r] *= sfr[r];

    // PV: O[q][d] += P[q][k] * V^T[d][k]  (V fragments direct from global, natural cols)
    const bf16x8 pf0 = *reinterpret_cast<const bf16x8*>(&Plds[w][lr][((2 * lg) ^ (lr & 14)) << 2]);
    const bf16x8 pf1 = *reinterpret_cast<const bf16x8*>(&Plds[w][lr][((8 + 2 * lg) ^ (lr & 14)) << 2]);
    const u16* vp = vput + kb0;
    __builtin_amdgcn_s_setprio(1);
#pragma unroll
    for (int nd = 0; nd < 4; ++nd) {
      bf16x8 vf0 = *reinterpret_cast<const bf16x8*>(vp + (size_t)nd * 16 * NS);
      bf16x8 vf1 = *reinterpret_cast<const bf16x8*>(vp + (size_t)nd * 16 * NS + 32);
      oacc[nd] = __builtin_amdgcn_mfma_f32_16x16x32_bf16(pf0, vf0, oacc[nd], 0, 0, 0);
      oacc[nd] = __builtin_amdgcn_mfma_f32_16x16x32_bf16(pf1, vf1, oacc[nd], 0, 0, 0);
    }
    __builtin_amdgcn_s_setprio(0);

    mw = mwn;
  }

  float il[4];
#pragma unroll
  for (int r = 0; r < 4; ++r) il[r] = 1.f / __shfl(l_s, lg * 4 + r);
#pragma unroll
  for (int nd = 0; nd < 4; ++nd)
#pragma unroll
    for (int r = 0; r < 4; ++r) {
      const int i = qbase + w * 16 + lg * 4 + r;
      attnout[(size_t)(b * NS + i) * ND + h * HD + nd * 16 + lr] = bfbits(oacc[nd][r] * il[r]);
    }
}

// ---------------- launch ----------------
extern "C" void kernel_launch(void* const* d_in, const int* in_sizes, int n_in,
                              void* d_out, int out_size, void* d_ws, size_t ws_size,
                              hipStream_t stream) {
  const float* x = (const float*)d_in[0];
  const int* bar = (const int*)d_in[1];
  const int* inst = (const int*)d_in[2];
  const int* lidx = (const int*)d_in[3];
  const float* Wq = (const float*)d_in[4];
  const float* bq = (const float*)d_in[5];
  const float* Wk = (const float*)d_in[6];
  const float* bk = (const float*)d_in[7];
  const float* Wv = (const float*)d_in[8];
  const float* bv = (const float*)d_in[9];
  const float* Wo = (const float*)d_in[10];
  const float* bo = (const float*)d_in[11];
  float* out = (float*)d_out;

  char* ws = (char*)d_ws;
  constexpr size_t XB = (size_t)NB * NS * ND * 2;   // 8 MB bf16 token-major buffer
  constexpr size_t WT = (size_t)ND * ND * 2;        // 2 MB
  u16* xb   = (u16*)(ws);
  u16* WqT  = (u16*)(ws + XB);                      // WqT|WkT|WvT contiguous = [3072][1024]
  u16* WkT  = (u16*)(ws + XB + 1 * WT);
  u16* WvT  = (u16*)(ws + XB + 2 * WT);
  u16* WoT  = (u16*)(ws + XB + 3 * WT);
  u16* qbuf = (u16*)(ws + XB + 4 * WT);
  u16* kbuf = (u16*)(ws + XB + 4 * WT + XB);
  u16* vtbuf= (u16*)(ws + XB + 4 * WT + 2 * XB);
  float* cost = (float*)(ws + XB + 4 * WT + 3 * XB);
  float* sint = cost + NS * 32;
  u64* maskbuf = (u64*)(ws + XB + 4 * WT + 3 * XB + (size_t)NS * 32 * 4 * 2);  // 1 MB
  u16* attnout = xb;  // alias: xb is dead after the QKV GEMM (stream-ordered)

  prep_weight4<<<dim3(32, 32, 4), dim3(32, 8), 0, stream>>>(Wq, Wk, Wv, Wo, WqT, WkT, WvT, WoT);
  convert_x<<<(NB * NS * ND / 4) / 256, 256, 0, stream>>>(x, xb);
  rope_tables<<<(NS * 32) / 256, 256, 0, stream>>>(cost, sint);
  build_mask<<<dim3(NB * NS / 4), 256, 0, stream>>>(bar, inst, lidx, maskbuf);

  gemm_qkv<<<dim3(24, 32), 256, 0, stream>>>(xb, WqT, bq, bk, bv, qbuf, kbuf, vtbuf, cost, sint);

  attn_fused<<<dim3(16, NH, NB), 512, 0, stream>>>(qbuf, kbuf, vtbuf, maskbuf, attnout);

  gemm_out<<<dim3(16, 32), 256, 0, stream>>>(attnout, WoT, bo, out);
}

// Round 7
// 157.288 us; speedup vs baseline: 1.5556x; 1.5556x over previous
//
#include <hip/hip_runtime.h>
#include <hip/hip_bf16.h>

typedef unsigned short u16;
typedef unsigned long long u64;
typedef float f32x4 __attribute__((ext_vector_type(4)));
typedef __bf16 bf16x8 __attribute__((ext_vector_type(8)));

#define NB 2
#define NS 2048
#define ND 1024
#define NH 16
#define HD 64

__device__ inline u16 bfbits(float f) { __bf16 h = (__bf16)f; return __builtin_bit_cast(u16, h); }

__device__ inline void gl16(const u16* g, u16* l) {
  __builtin_amdgcn_global_load_lds((const __attribute__((address_space(1))) void*)(g),
                                   (__attribute__((address_space(3))) void*)(l), 16, 0, 0);
}

// ---------------- prep kernels ----------------

// transpose W [K][N] f32 -> WT [N][K] bf16 bits; blockIdx.z selects which weight
__global__ void __launch_bounds__(256)
prep_weight4(const float* __restrict__ W0, const float* __restrict__ W1,
             const float* __restrict__ W2, const float* __restrict__ W3,
             u16* __restrict__ T0, u16* __restrict__ T1, u16* __restrict__ T2, u16* __restrict__ T3) {
  __shared__ float tile[32][33];
  const float* Ws[4] = {W0, W1, W2, W3};
  u16* Ts[4] = {T0, T1, T2, T3};
  const float* __restrict__ W = Ws[blockIdx.z];
  u16* __restrict__ WT = Ts[blockIdx.z];
  const int tx = threadIdx.x, ty = threadIdx.y;
  const int n0 = blockIdx.x * 32, k0 = blockIdx.y * 32;
#pragma unroll
  for (int i = 0; i < 4; ++i)
    tile[ty + i * 8][tx] = W[(size_t)(k0 + ty + i * 8) * ND + n0 + tx];
  __syncthreads();
#pragma unroll
  for (int i = 0; i < 4; ++i)
    WT[(size_t)(n0 + ty + i * 8) * ND + k0 + tx] = bfbits(tile[tx][ty + i * 8]);
}

__global__ void __launch_bounds__(256)
convert_x(const float* __restrict__ x, u16* __restrict__ xb) {
  const int i = blockIdx.x * 256 + threadIdx.x;  // over NB*NS*ND/4
  float4 v = reinterpret_cast<const float4*>(x)[i];
  uint2 pk;
  pk.x = (unsigned)bfbits(v.x) | ((unsigned)bfbits(v.y) << 16);
  pk.y = (unsigned)bfbits(v.z) | ((unsigned)bfbits(v.w) << 16);
  reinterpret_cast<uint2*>(xb)[i] = pk;
}

__global__ void __launch_bounds__(256)
rope_tables(float* __restrict__ cost, float* __restrict__ sint) {
  const int i = blockIdx.x * 256 + threadIdx.x;  // NS*32
  const int s = i >> 5, d = i & 31;
  float invf = powf(10000.f, -(float)d / 32.f);
  float a = (float)s * invf;
  cost[i] = cosf(a);
  sint[i] = sinf(a);
}

// visibility bitmask: mb[(b*NS+q)*32 + kt] bit l = vis(q, kt*64+l). one wave per q-row.
// attn uses 128-row q-tiles; fill through the tile's end (ktmax = (q>>7)*2 + 1); entries past
// the row's own causal extent are correct zeros (ballot evaluates k > q -> vis=false).
__global__ void __launch_bounds__(256)
build_mask(const int* __restrict__ bar, const int* __restrict__ inst,
           const int* __restrict__ lidx, u64* __restrict__ mb) {
  const int w = threadIdx.x >> 6, lane = threadIdx.x & 63;
  const int pair = blockIdx.x * 4 + w;
  const int b = pair >> 11, q = pair & (NS - 1);
  const bool fc = (lidx[0] < 4);
  const int qb = bar[b * NS + q], qi = inst[b * NS + q];
  const int ktmax = ((q >> 7) << 1) + 1;  // cover the full 128-row q-tile's key range
  for (int kt = 0; kt <= ktmax; ++kt) {
    const int k = (kt << 6) + lane;
    const int kbv = bar[b * NS + k], kiv = inst[b * NS + k];
    bool vis;
    if (k > q) {
      vis = false;
    } else if (!fc) {
      vis = true;
    } else {
      const bool kreal = kiv < 129, qreal = qi < 129;
      int off = kbv - qb;
      off = off < -64 ? -64 : (off > 64 ? 64 : off);
      const bool rule = (kiv == qi) ? (off >= 0) : ((off >= 0 && off <= 2) || off == 4);
      vis = (kreal && qreal && rule) || (kiv == 129) || (kbv == -1);
    }
    const u64 wd = __ballot(vis);
    if (lane == 0) mb[(((size_t)b * NS + q) << 5) + kt] = wd;
  }
}

// ---------------- fused QKV GEMM ----------------
// A [4096][1024] bf16, BT3 [3072][1024] bf16 (WqT|WkT|WvT contiguous).
// grid (24, 32): blockIdx.x>>3 = projection (0:q rope, 1:k rope, 2:v transpose).
// 768 blocks = 3/CU. T4: raw s_barrier + counted vmcnt(4) -- prefetch stays in flight
// across the barrier instead of draining to 0 every K-step.
__global__ void __launch_bounds__(256)
gemm_qkv(const u16* __restrict__ A, const u16* __restrict__ BT3,
         const float* __restrict__ bq, const float* __restrict__ bk, const float* __restrict__ bv,
         u16* __restrict__ qbuf, u16* __restrict__ kbuf, u16* __restrict__ vtbuf,
         const float* __restrict__ cost, const float* __restrict__ sint) {
  constexpr int K = ND;
  __shared__ alignas(16) u16 Alds[2][128][32];
  __shared__ alignas(16) u16 Blds[2][128][32];
  const int t = threadIdx.x;
  const int bx = blockIdx.x;
  const int proj = bx >> 3;
  const int n0 = (bx & 7) * 128;
  const int m0 = blockIdx.y * 128;
  const int w = t >> 6, lane = t & 63, lr = lane & 15, lg = lane >> 4;
  const int wr = w >> 1, wc = w & 1;
  const float* __restrict__ bias = proj == 0 ? bq : (proj == 1 ? bk : bv);
  f32x4 acc[4][4] = {};

  const int srow = lane >> 2;       // 0..15
  const int scol = (lane & 3) * 8;  // u16 offset
  const u16* Ag = A + (size_t)(m0 + w * 32 + srow) * K + scol;
  const u16* Bg = BT3 + (size_t)(proj * ND + n0 + w * 32 + srow) * K + scol;

  // prologue: stage k0=0 into buf 0
  gl16(Ag, &Alds[0][w * 32][0]);
  gl16(Ag + 16 * K, &Alds[0][w * 32 + 16][0]);
  gl16(Bg, &Blds[0][w * 32][0]);
  gl16(Bg + 16 * K, &Blds[0][w * 32 + 16][0]);

  int cur = 0;
  for (int k0 = 0; k0 < K; k0 += 32) {
    __builtin_amdgcn_s_barrier();  // all waves done reading buf[cur^1]; no vmcnt drain
    if (k0 + 32 < K) {
      gl16(Ag + k0 + 32, &Alds[cur ^ 1][w * 32][0]);
      gl16(Ag + k0 + 32 + 16 * K, &Alds[cur ^ 1][w * 32 + 16][0]);
      gl16(Bg + k0 + 32, &Blds[cur ^ 1][w * 32][0]);
      gl16(Bg + k0 + 32 + 16 * K, &Blds[cur ^ 1][w * 32 + 16][0]);
      asm volatile("s_waitcnt vmcnt(4)" ::: "memory");  // prev tile's 4 loads landed
    } else {
      asm volatile("s_waitcnt vmcnt(0)" ::: "memory");
    }
    __builtin_amdgcn_sched_barrier(0);
    bf16x8 af[4], bfr[4];
#pragma unroll
    for (int i = 0; i < 4; ++i)
      af[i] = *reinterpret_cast<const bf16x8*>(&Alds[cur][wr * 64 + i * 16 + lr][lg * 8]);
#pragma unroll
    for (int i = 0; i < 4; ++i)
      bfr[i] = *reinterpret_cast<const bf16x8*>(&Blds[cur][wc * 64 + i * 16 + lr][lg * 8]);
#pragma unroll
    for (int mi = 0; mi < 4; ++mi)
#pragma unroll
      for (int ni = 0; ni < 4; ++ni)
        acc[mi][ni] = __builtin_amdgcn_mfma_f32_16x16x32_bf16(af[mi], bfr[ni], acc[mi][ni], 0, 0, 0);
    cur ^= 1;
  }

  if (proj < 2) {
    u16* out = proj ? kbuf : qbuf;
    const float qs = proj == 0 ? 0.125f : 1.0f;  // fold attn scale HD^-0.5 into q
    const int colbase = n0 + wc * 64;
    const int h = colbase >> 6;  // wave's 64 cols = one head
#pragma unroll
    for (int mi = 0; mi < 4; ++mi)
#pragma unroll
      for (int r = 0; r < 4; ++r) {
        const int row = m0 + wr * 64 + mi * 16 + lg * 4 + r;
        const int b = row >> 11, s = row & (NS - 1);
        u16* op = out + ((size_t)(b * NH + h) * NS + s) * HD;
#pragma unroll
        for (int nf = 0; nf < 2; ++nf) {
          const int dlo = nf * 16 + lr;  // < 32
          float lo = acc[mi][nf][r] + bias[colbase + dlo];
          float hi = acc[mi][nf + 2][r] + bias[colbase + dlo + 32];
          float c = cost[s * 32 + dlo], si = sint[s * 32 + dlo];
          op[dlo] = bfbits((lo * c - hi * si) * qs);
          op[dlo + 32] = bfbits((hi * c + lo * si) * qs);
        }
      }
  } else {
    u16* out = vtbuf;
#pragma unroll
    for (int mi = 0; mi < 4; ++mi)
#pragma unroll
      for (int r = 0; r < 4; ++r) {
        const int row = m0 + wr * 64 + mi * 16 + lg * 4 + r;
        const int b = row >> 11, s = row & (NS - 1);
#pragma unroll
        for (int ni = 0; ni < 4; ++ni) {
          const int col = n0 + wc * 64 + ni * 16 + lr;
          const int h = col >> 6, d = col & 63;
          out[((size_t)(b * NH + h) * HD + d) * NS + s] = bfbits(acc[mi][ni][r] + bias[col]);
        }
      }
  }
}

// ---------------- output GEMM (C = A*B^T + bias, f32 out), BM=128 BN=64 ----------------
// grid (16, 32) = 512 blocks = 2/CU. T4 counted vmcnt(3) as above.
__global__ void __launch_bounds__(256)
gemm_out(const u16* __restrict__ A, const u16* __restrict__ BT, const float* __restrict__ bias,
         float* __restrict__ out) {
  constexpr int K = ND;
  __shared__ alignas(16) u16 Alds[2][128][32];
  __shared__ alignas(16) u16 Blds[2][64][32];
  const int t = threadIdx.x;
  const int n0 = blockIdx.x * 64;
  const int m0 = blockIdx.y * 128;
  const int w = t >> 6, lane = t & 63, lr = lane & 15, lg = lane >> 4;
  f32x4 acc[2][4] = {};

  const int srow = lane >> 2;
  const int scol = (lane & 3) * 8;
  const u16* Ag = A + (size_t)(m0 + w * 32 + srow) * K + scol;
  const u16* Bg = BT + (size_t)(n0 + w * 16 + srow) * K + scol;

  gl16(Ag, &Alds[0][w * 32][0]);
  gl16(Ag + 16 * K, &Alds[0][w * 32 + 16][0]);
  gl16(Bg, &Blds[0][w * 16][0]);

  int cur = 0;
  for (int k0 = 0; k0 < K; k0 += 32) {
    __builtin_amdgcn_s_barrier();
    if (k0 + 32 < K) {
      gl16(Ag + k0 + 32, &Alds[cur ^ 1][w * 32][0]);
      gl16(Ag + k0 + 32 + 16 * K, &Alds[cur ^ 1][w * 32 + 16][0]);
      gl16(Bg + k0 + 32, &Blds[cur ^ 1][w * 16][0]);
      asm volatile("s_waitcnt vmcnt(3)" ::: "memory");
    } else {
      asm volatile("s_waitcnt vmcnt(0)" ::: "memory");
    }
    __builtin_amdgcn_sched_barrier(0);
    bf16x8 af[2], bfr[4];
#pragma unroll
    for (int i = 0; i < 2; ++i)
      af[i] = *reinterpret_cast<const bf16x8*>(&Alds[cur][w * 32 + i * 16 + lr][lg * 8]);
#pragma unroll
    for (int i = 0; i < 4; ++i)
      bfr[i] = *reinterpret_cast<const bf16x8*>(&Blds[cur][i * 16 + lr][lg * 8]);
#pragma unroll
    for (int mi = 0; mi < 2; ++mi)
#pragma unroll
      for (int ni = 0; ni < 4; ++ni)
        acc[mi][ni] = __builtin_amdgcn_mfma_f32_16x16x32_bf16(af[mi], bfr[ni], acc[mi][ni], 0, 0, 0);
    cur ^= 1;
  }

#pragma unroll
  for (int mi = 0; mi < 2; ++mi)
#pragma unroll
    for (int r = 0; r < 4; ++r) {
      const int row = m0 + w * 32 + mi * 16 + lg * 4 + r;
#pragma unroll
      for (int ni = 0; ni < 4; ++ni) {
        const int col = n0 + ni * 16 + lr;
        out[(size_t)row * ND + col] = acc[mi][ni][r] + bias[col];
      }
    }
}

// ---------------- fused masked flash attention (v6: v4b + counted vmcnt + defer-max) --------
// grid (16, NH, NB) = 512 blocks x 8 waves, 128-row q-tiles, dbuf K/V via global_load_lds.
// Per tile: raw s_barrier (no drain) -> issue next-tile gl16s -> s_waitcnt vmcnt(2) (current
// tile's 2 loads landed; next tile's stay in flight under compute). Q arrives pre-scaled by
// 0.125 from gemm_qkv. Defer-max (T13, THR=8) skips the O-rescale + 4 bpermutes most tiles.
__global__ void __launch_bounds__(512, 4)
attn_fused(const u16* __restrict__ qb, const u16* __restrict__ kb, const u16* __restrict__ vtb,
           const u64* __restrict__ mb, u16* __restrict__ attnout) {
  __shared__ alignas(16) u16 Klds[2][64][64];   // [buf][k][d]  rows 128B, swizzled 16B units
  __shared__ alignas(16) u16 Vlds[2][64][64];   // [buf][d][k]
  __shared__ alignas(16) u16 Plds[8][16][64];   // per-wave P [q][k], swizzled 8B units
  const int t = threadIdx.x, w = t >> 6, lane = t & 63, lr = lane & 15, lg = lane >> 4;
  const int h = blockIdx.y, b = blockIdx.z;
  const int qt = b ? (int)blockIdx.x : 15 - (int)blockIdx.x;  // complementary pairs per CU
  const int qbase = qt * 128;
  const u16* __restrict__ qh = qb + (size_t)(b * NH + h) * NS * HD;
  const u16* __restrict__ kh = kb + (size_t)(b * NH + h) * NS * HD;
  const u16* __restrict__ vth = vtb + (size_t)(b * NH + h) * HD * NS;

  // staging: wave w stages rows w*8..w*8+7 of K and of V (one gl16 each).
  // LDS linear, global source pre-swizzled: 16B unit col' = col ^ (row&7); row&7 == srow.
  const int srow = lane >> 3;  // 0..7
  const int lcol = (lane & 7) ^ srow;
  const int sw = lr & 7;

  // Q fragments (B-operand of swapped QK^T): rows q = qbase + w*16 + lr
  const int qrow = qbase + w * 16 + lr;
  const bf16x8 qf0 = *reinterpret_cast<const bf16x8*>(qh + (size_t)qrow * HD + lg * 8);
  const bf16x8 qf1 = *reinterpret_cast<const bf16x8*>(qh + (size_t)qrow * HD + 32 + lg * 8);
  const u64* __restrict__ mrow = mb + (((size_t)b * NS + qrow) << 5);

  float m_s = -1e30f, l_s = 0.f;
  f32x4 oacc[4] = {};
  const int nt = 2 * qt + 2;  // causal: keys < qbase+128
  int cur = 0;

  // prologue: stage tile 0
  {
    const int row = w * 8 + srow;
    gl16(kh + (size_t)row * HD + lcol * 8, &Klds[0][w * 8][0]);
    gl16(vth + (size_t)row * NS + lcol * 8, &Vlds[0][w * 8][0]);
  }
  u64 mw = mrow[0];

  for (int kt = 0; kt < nt; ++kt) {
    __builtin_amdgcn_s_barrier();  // all waves done reading buf[cur^1]; no vmcnt drain
    if (kt + 1 < nt) {
      const int kb0n = (kt + 1) * 64;
      const int row = w * 8 + srow;
      gl16(kh + (size_t)(kb0n + row) * HD + lcol * 8, &Klds[cur ^ 1][w * 8][0]);
      gl16(vth + (size_t)row * NS + kb0n + lcol * 8, &Vlds[cur ^ 1][w * 8][0]);
      asm volatile("s_waitcnt vmcnt(2)" ::: "memory");  // buf[cur]'s 2 loads landed
    } else {
      asm volatile("s_waitcnt vmcnt(0)" ::: "memory");
    }
    __builtin_amdgcn_sched_barrier(0);
    const u64 mwn = (kt + 1 < nt) ? mrow[kt + 1] : 0ULL;

    const u16* Kb = &Klds[cur][0][0];
    const u16* Vb = &Vlds[cur][0][0];

    // S^T = K * Q^T : sacc[n][r] = S[q = qrow][k = kt*64 + n*16 + lg*4 + r] (pre-scaled)
    f32x4 sacc[4] = {};
    __builtin_amdgcn_s_setprio(1);
#pragma unroll
    for (int n = 0; n < 4; ++n) {
      const u16* kr = Kb + (n * 16 + lr) * 64;
      bf16x8 kf0 = *reinterpret_cast<const bf16x8*>(kr + ((lg ^ sw) << 3));
      bf16x8 kf1 = *reinterpret_cast<const bf16x8*>(kr + (((4 + lg) ^ sw) << 3));
      sacc[n] = __builtin_amdgcn_mfma_f32_16x16x32_bf16(kf0, qf0, sacc[n], 0, 0, 0);
      sacc[n] = __builtin_amdgcn_mfma_f32_16x16x32_bf16(kf1, qf1, sacc[n], 0, 0, 0);
    }
    __builtin_amdgcn_s_setprio(0);

    // mask (bit test) + tree row-max. masked -> -3e30 so exp underflows even vs m = -1e30.
    float pm[4][4];
    float mx4[4];
#pragma unroll
    for (int n = 0; n < 4; ++n) {
#pragma unroll
      for (int r = 0; r < 4; ++r) {
        const bool vis = (mw >> (n * 16 + lg * 4 + r)) & 1ULL;
        pm[n][r] = vis ? sacc[n][r] : -3e30f;
      }
      mx4[n] = fmaxf(fmaxf(pm[n][0], pm[n][1]), fmaxf(pm[n][2], pm[n][3]));
    }
    float mx = fmaxf(fmaxf(mx4[0], mx4[1]), fmaxf(mx4[2], mx4[3]));
    mx = fmaxf(mx, __shfl_xor(mx, 16));
    mx = fmaxf(mx, __shfl_xor(mx, 32));

    // defer-max: if no row grew past m+8, keep old max (skip rescale entirely)
    const bool skip = __all(mx <= m_s + 8.f);
    const float mn = skip ? m_s : fmaxf(m_s, mx);

    // exp + pack P to per-wave Plds (row q=lr, 4 consecutive k per b64 write, swizzled)
    float rs = 0.f;
#pragma unroll
    for (int n = 0; n < 4; ++n) {
      const float e0 = __expf(pm[n][0] - mn);
      const float e1 = __expf(pm[n][1] - mn);
      const float e2 = __expf(pm[n][2] - mn);
      const float e3 = __expf(pm[n][3] - mn);
      rs += (e0 + e1) + (e2 + e3);
      uint2 pk;
      pk.x = (unsigned)bfbits(e0) | ((unsigned)bfbits(e1) << 16);
      pk.y = (unsigned)bfbits(e2) | ((unsigned)bfbits(e3) << 16);
      *reinterpret_cast<uint2*>(&Plds[w][lr][(((n << 2) + lg) ^ (lr & 14)) << 2]) = pk;
    }
    rs += __shfl_xor(rs, 16);
    rs += __shfl_xor(rs, 32);

    if (skip) {
      l_s += rs;
    } else {
      const float sf = __expf(m_s - mn);
      m_s = mn;
      l_s = l_s * sf + rs;
      float sfr[4];
#pragma unroll
      for (int r = 0; r < 4; ++r) sfr[r] = __shfl(sf, lg * 4 + r);
#pragma unroll
      for (int nd = 0; nd < 4; ++nd)
#pragma unroll
        for (int r = 0; r < 4; ++r) oacc[nd][r] *= sfr[r];
    }

    // PV: O[q][d] += P[q][k] * V^T[d][k]
    const bf16x8 pf0 = *reinterpret_cast<const bf16x8*>(&Plds[w][lr][((2 * lg) ^ (lr & 14)) << 2]);
    const bf16x8 pf1 = *reinterpret_cast<const bf16x8*>(&Plds[w][lr][((8 + 2 * lg) ^ (lr & 14)) << 2]);
    __builtin_amdgcn_s_setprio(1);
#pragma unroll
    for (int nd = 0; nd < 4; ++nd) {
      const u16* vr = Vb + (nd * 16 + lr) * 64;
      bf16x8 vf0 = *reinterpret_cast<const bf16x8*>(vr + ((lg ^ sw) << 3));
      bf16x8 vf1 = *reinterpret_cast<const bf16x8*>(vr + (((4 + lg) ^ sw) << 3));
      oacc[nd] = __builtin_amdgcn_mfma_f32_16x16x32_bf16(pf0, vf0, oacc[nd], 0, 0, 0);
      oacc[nd] = __builtin_amdgcn_mfma_f32_16x16x32_bf16(pf1, vf1, oacc[nd], 0, 0, 0);
    }
    __builtin_amdgcn_s_setprio(0);

    mw = mwn;
    cur ^= 1;
  }

  float il[4];
#pragma unroll
  for (int r = 0; r < 4; ++r) il[r] = 1.f / __shfl(l_s, lg * 4 + r);
#pragma unroll
  for (int nd = 0; nd < 4; ++nd)
#pragma unroll
    for (int r = 0; r < 4; ++r) {
      const int i = qbase + w * 16 + lg * 4 + r;
      attnout[(size_t)(b * NS + i) * ND + h * HD + nd * 16 + lr] = bfbits(oacc[nd][r] * il[r]);
    }
}

// ---------------- launch ----------------
extern "C" void kernel_launch(void* const* d_in, const int* in_sizes, int n_in,
                              void* d_out, int out_size, void* d_ws, size_t ws_size,
                              hipStream_t stream) {
  const float* x = (const float*)d_in[0];
  const int* bar = (const int*)d_in[1];
  const int* inst = (const int*)d_in[2];
  const int* lidx = (const int*)d_in[3];
  const float* Wq = (const float*)d_in[4];
  const float* bq = (const float*)d_in[5];
  const float* Wk = (const float*)d_in[6];
  const float* bk = (const float*)d_in[7];
  const float* Wv = (const float*)d_in[8];
  const float* bv = (const float*)d_in[9];
  const float* Wo = (const float*)d_in[10];
  const float* bo = (const float*)d_in[11];
  float* out = (float*)d_out;

  char* ws = (char*)d_ws;
  constexpr size_t XB = (size_t)NB * NS * ND * 2;   // 8 MB bf16 token-major buffer
  constexpr size_t WT = (size_t)ND * ND * 2;        // 2 MB
  u16* xb   = (u16*)(ws);
  u16* WqT  = (u16*)(ws + XB);                      // WqT|WkT|WvT contiguous = [3072][1024]
  u16* WkT  = (u16*)(ws + XB + 1 * WT);
  u16* WvT  = (u16*)(ws + XB + 2 * WT);
  u16* WoT  = (u16*)(ws + XB + 3 * WT);
  u16* qbuf = (u16*)(ws + XB + 4 * WT);
  u16* kbuf = (u16*)(ws + XB + 4 * WT + XB);
  u16* vtbuf= (u16*)(ws + XB + 4 * WT + 2 * XB);
  float* cost = (float*)(ws + XB + 4 * WT + 3 * XB);
  float* sint = cost + NS * 32;
  u64* maskbuf = (u64*)(ws + XB + 4 * WT + 3 * XB + (size_t)NS * 32 * 4 * 2);  // 1 MB
  u16* attnout = xb;  // alias: xb is dead after the QKV GEMM (stream-ordered)

  prep_weight4<<<dim3(32, 32, 4), dim3(32, 8), 0, stream>>>(Wq, Wk, Wv, Wo, WqT, WkT, WvT, WoT);
  convert_x<<<(NB * NS * ND / 4) / 256, 256, 0, stream>>>(x, xb);
  rope_tables<<<(NS * 32) / 256, 256, 0, stream>>>(cost, sint);
  build_mask<<<dim3(NB * NS / 4), 256, 0, stream>>>(bar, inst, lidx, maskbuf);

  gemm_qkv<<<dim3(24, 32), 256, 0, stream>>>(xb, WqT, bq, bk, bv, qbuf, kbuf, vtbuf, cost, sint);

  attn_fused<<<dim3(16, NH, NB), 512, 0, stream>>>(qbuf, kbuf, vtbuf, maskbuf, attnout);

  gemm_out<<<dim3(16, 32), 256, 0, stream>>>(attnout, WoT, bo, out);
}

// Round 8
// 147.237 us; speedup vs baseline: 1.6618x; 1.0683x over previous
//
#include <hip/hip_runtime.h>
#include <hip/hip_bf16.h>

typedef unsigned short u16;
typedef unsigned long long u64;
typedef float f32x4 __attribute__((ext_vector_type(4)));
typedef __bf16 bf16x8 __attribute__((ext_vector_type(8)));

#define NB 2
#define NS 2048
#define ND 1024
#define NH 16
#define HD 64

__device__ inline u16 bfbits(float f) { __bf16 h = (__bf16)f; return __builtin_bit_cast(u16, h); }

__device__ inline void gl16(const u16* g, u16* l) {
  __builtin_amdgcn_global_load_lds((const __attribute__((address_space(1))) void*)(g),
                                   (__attribute__((address_space(3))) void*)(l), 16, 0, 0);
}

// ---------------- prep kernels ----------------

// transpose W [K][N] f32 -> WT [N][K] bf16 bits; blockIdx.z selects which weight
__global__ void __launch_bounds__(256)
prep_weight4(const float* __restrict__ W0, const float* __restrict__ W1,
             const float* __restrict__ W2, const float* __restrict__ W3,
             u16* __restrict__ T0, u16* __restrict__ T1, u16* __restrict__ T2, u16* __restrict__ T3) {
  __shared__ float tile[32][33];
  const float* Ws[4] = {W0, W1, W2, W3};
  u16* Ts[4] = {T0, T1, T2, T3};
  const float* __restrict__ W = Ws[blockIdx.z];
  u16* __restrict__ WT = Ts[blockIdx.z];
  const int tx = threadIdx.x, ty = threadIdx.y;
  const int n0 = blockIdx.x * 32, k0 = blockIdx.y * 32;
#pragma unroll
  for (int i = 0; i < 4; ++i)
    tile[ty + i * 8][tx] = W[(size_t)(k0 + ty + i * 8) * ND + n0 + tx];
  __syncthreads();
#pragma unroll
  for (int i = 0; i < 4; ++i)
    WT[(size_t)(n0 + ty + i * 8) * ND + k0 + tx] = bfbits(tile[tx][ty + i * 8]);
}

// fused: bf16-convert x (blocks 0..8191) + rope tables (blocks 8192..8447)
__global__ void __launch_bounds__(256)
convert_x_rope(const float* __restrict__ x, u16* __restrict__ xb,
               float* __restrict__ cost, float* __restrict__ sint) {
  const int bx = blockIdx.x;
  if (bx < (NB * NS * ND / 4) / 256) {
    const int i = bx * 256 + threadIdx.x;  // over NB*NS*ND/4
    float4 v = reinterpret_cast<const float4*>(x)[i];
    uint2 pk;
    pk.x = (unsigned)bfbits(v.x) | ((unsigned)bfbits(v.y) << 16);
    pk.y = (unsigned)bfbits(v.z) | ((unsigned)bfbits(v.w) << 16);
    reinterpret_cast<uint2*>(xb)[i] = pk;
  } else {
    const int i = (bx - (NB * NS * ND / 4) / 256) * 256 + threadIdx.x;  // NS*32
    const int s = i >> 5, d = i & 31;
    float invf = powf(10000.f, -(float)d / 32.f);
    float a = (float)s * invf;
    cost[i] = cosf(a);
    sint[i] = sinf(a);
  }
}

// visibility bitmask: mb[(b*NS+q)*32 + kt] bit l = vis(q, kt*64+l). one wave per q-row.
// attn uses 128-row q-tiles; fill through the tile's end (ktmax = (q>>7)*2 + 1); entries past
// the row's own causal extent are correct zeros (ballot evaluates k > q -> vis=false).
__global__ void __launch_bounds__(256)
build_mask(const int* __restrict__ bar, const int* __restrict__ inst,
           const int* __restrict__ lidx, u64* __restrict__ mb) {
  const int w = threadIdx.x >> 6, lane = threadIdx.x & 63;
  const int pair = blockIdx.x * 4 + w;
  const int b = pair >> 11, q = pair & (NS - 1);
  const bool fc = (lidx[0] < 4);
  const int qb = bar[b * NS + q], qi = inst[b * NS + q];
  const int ktmax = ((q >> 7) << 1) + 1;  // cover the full 128-row q-tile's key range
  for (int kt = 0; kt <= ktmax; ++kt) {
    const int k = (kt << 6) + lane;
    const int kbv = bar[b * NS + k], kiv = inst[b * NS + k];
    bool vis;
    if (k > q) {
      vis = false;
    } else if (!fc) {
      vis = true;
    } else {
      const bool kreal = kiv < 129, qreal = qi < 129;
      int off = kbv - qb;
      off = off < -64 ? -64 : (off > 64 ? 64 : off);
      const bool rule = (kiv == qi) ? (off >= 0) : ((off >= 0 && off <= 2) || off == 4);
      vis = (kreal && qreal && rule) || (kiv == 129) || (kbv == -1);
    }
    const u64 wd = __ballot(vis);
    if (lane == 0) mb[(((size_t)b * NS + q) << 5) + kt] = wd;
  }
}

// ---------------- fused QKV GEMM ----------------
// A [4096][1024] bf16, BT3 [3072][1024] bf16 (WqT|WkT|WvT contiguous).
// grid (24, 32) = 768 blocks = 3/CU; T4 counted vmcnt; dbuf LDS.
// T1 XCD-chunk: each XCD owns an 8-mtile x 12-(proj,n)-panel rect: A-tile stays hot in its L2
// (1 x 256KB working tile), B panels (12 x 256KB = 3MB) resident -> A HBM refetch 64MB -> ~16MB.
__global__ void __launch_bounds__(256)
gemm_qkv(const u16* __restrict__ A, const u16* __restrict__ BT3,
         const float* __restrict__ bq, const float* __restrict__ bk, const float* __restrict__ bv,
         u16* __restrict__ qbuf, u16* __restrict__ kbuf, u16* __restrict__ vtbuf,
         const float* __restrict__ cost, const float* __restrict__ sint) {
  constexpr int K = ND;
  __shared__ alignas(16) u16 Alds[2][128][32];
  __shared__ alignas(16) u16 Blds[2][128][32];
  const int t = threadIdx.x;
  const int hid = (int)blockIdx.x + 24 * (int)blockIdx.y;  // 0..767
  const int xcd = hid & 7, j = hid >> 3;                   // j 0..95
  const int m0 = ((xcd >> 1) * 8 + j / 12) * 128;          // 32 m-tiles
  const int pn = (xcd & 1) * 12 + j % 12;                  // 24 (proj,n) panels
  const int proj = pn >> 3;
  const int n0 = (pn & 7) * 128;
  const int w = t >> 6, lane = t & 63, lr = lane & 15, lg = lane >> 4;
  const int wr = w >> 1, wc = w & 1;
  const float* __restrict__ bias = proj == 0 ? bq : (proj == 1 ? bk : bv);
  f32x4 acc[4][4] = {};

  const int srow = lane >> 2;       // 0..15
  const int scol = (lane & 3) * 8;  // u16 offset
  const u16* Ag = A + (size_t)(m0 + w * 32 + srow) * K + scol;
  const u16* Bg = BT3 + (size_t)(proj * ND + n0 + w * 32 + srow) * K + scol;

  // prologue: stage k0=0 into buf 0
  gl16(Ag, &Alds[0][w * 32][0]);
  gl16(Ag + 16 * K, &Alds[0][w * 32 + 16][0]);
  gl16(Bg, &Blds[0][w * 32][0]);
  gl16(Bg + 16 * K, &Blds[0][w * 32 + 16][0]);

  int cur = 0;
  for (int k0 = 0; k0 < K; k0 += 32) {
    __builtin_amdgcn_s_barrier();  // all waves done reading buf[cur^1]; no vmcnt drain
    if (k0 + 32 < K) {
      gl16(Ag + k0 + 32, &Alds[cur ^ 1][w * 32][0]);
      gl16(Ag + k0 + 32 + 16 * K, &Alds[cur ^ 1][w * 32 + 16][0]);
      gl16(Bg + k0 + 32, &Blds[cur ^ 1][w * 32][0]);
      gl16(Bg + k0 + 32 + 16 * K, &Blds[cur ^ 1][w * 32 + 16][0]);
      asm volatile("s_waitcnt vmcnt(4)" ::: "memory");  // prev tile's 4 loads landed
    } else {
      asm volatile("s_waitcnt vmcnt(0)" ::: "memory");
    }
    __builtin_amdgcn_sched_barrier(0);
    bf16x8 af[4], bfr[4];
#pragma unroll
    for (int i = 0; i < 4; ++i)
      af[i] = *reinterpret_cast<const bf16x8*>(&Alds[cur][wr * 64 + i * 16 + lr][lg * 8]);
#pragma unroll
    for (int i = 0; i < 4; ++i)
      bfr[i] = *reinterpret_cast<const bf16x8*>(&Blds[cur][wc * 64 + i * 16 + lr][lg * 8]);
#pragma unroll
    for (int mi = 0; mi < 4; ++mi)
#pragma unroll
      for (int ni = 0; ni < 4; ++ni)
        acc[mi][ni] = __builtin_amdgcn_mfma_f32_16x16x32_bf16(af[mi], bfr[ni], acc[mi][ni], 0, 0, 0);
    cur ^= 1;
  }

  if (proj < 2) {
    u16* out = proj ? kbuf : qbuf;
    const float qs = proj == 0 ? 0.125f : 1.0f;  // fold attn scale HD^-0.5 into q
    const int colbase = n0 + wc * 64;
    const int h = colbase >> 6;  // wave's 64 cols = one head
#pragma unroll
    for (int mi = 0; mi < 4; ++mi)
#pragma unroll
      for (int r = 0; r < 4; ++r) {
        const int row = m0 + wr * 64 + mi * 16 + lg * 4 + r;
        const int b = row >> 11, s = row & (NS - 1);
        u16* op = out + ((size_t)(b * NH + h) * NS + s) * HD;
#pragma unroll
        for (int nf = 0; nf < 2; ++nf) {
          const int dlo = nf * 16 + lr;  // < 32
          float lo = acc[mi][nf][r] + bias[colbase + dlo];
          float hi = acc[mi][nf + 2][r] + bias[colbase + dlo + 32];
          float c = cost[s * 32 + dlo], si = sint[s * 32 + dlo];
          op[dlo] = bfbits((lo * c - hi * si) * qs);
          op[dlo + 32] = bfbits((hi * c + lo * si) * qs);
        }
      }
  } else {
    u16* out = vtbuf;
#pragma unroll
    for (int mi = 0; mi < 4; ++mi)
#pragma unroll
      for (int ni = 0; ni < 4; ++ni) {
        const int col = n0 + wc * 64 + ni * 16 + lr;
        const int h = col >> 6, d = col & 63;
        const int s0 = m0 + wr * 64 + mi * 16 + lg * 4;  // 4 consecutive s = r
        const int b = s0 >> 11, s = s0 & (NS - 1);
        uint2 pk;
        pk.x = (unsigned)bfbits(acc[mi][ni][0] + bias[col]) |
               ((unsigned)bfbits(acc[mi][ni][1] + bias[col]) << 16);
        pk.y = (unsigned)bfbits(acc[mi][ni][2] + bias[col]) |
               ((unsigned)bfbits(acc[mi][ni][3] + bias[col]) << 16);
        *reinterpret_cast<uint2*>(out + ((size_t)(b * NH + h) * HD + d) * NS + s) = pk;
      }
  }
}

// ---------------- output GEMM (C = A*B^T + bias, f32 out), BM=128 BN=64 ----------------
// grid (16, 32) = 512 blocks = 2/CU. T4 counted vmcnt. T1 XCD-chunk 8m x 8n rect:
// A per XCD 2MB + B 1MB resident -> A HBM refetch 64MB -> ~16MB.
__global__ void __launch_bounds__(256)
gemm_out(const u16* __restrict__ A, const u16* __restrict__ BT, const float* __restrict__ bias,
         float* __restrict__ out) {
  constexpr int K = ND;
  __shared__ alignas(16) u16 Alds[2][128][32];
  __shared__ alignas(16) u16 Blds[2][64][32];
  const int t = threadIdx.x;
  const int hid = (int)blockIdx.x + 16 * (int)blockIdx.y;  // 0..511
  const int xcd = hid & 7, j = hid >> 3;                   // j 0..63
  const int m0 = ((xcd >> 1) * 8 + (j >> 3)) * 128;        // 32 m-tiles
  const int n0 = ((xcd & 1) * 8 + (j & 7)) * 64;           // 16 n-tiles
  const int w = t >> 6, lane = t & 63, lr = lane & 15, lg = lane >> 4;
  f32x4 acc[2][4] = {};

  const int srow = lane >> 2;
  const int scol = (lane & 3) * 8;
  const u16* Ag = A + (size_t)(m0 + w * 32 + srow) * K + scol;
  const u16* Bg = BT + (size_t)(n0 + w * 16 + srow) * K + scol;

  gl16(Ag, &Alds[0][w * 32][0]);
  gl16(Ag + 16 * K, &Alds[0][w * 32 + 16][0]);
  gl16(Bg, &Blds[0][w * 16][0]);

  int cur = 0;
  for (int k0 = 0; k0 < K; k0 += 32) {
    __builtin_amdgcn_s_barrier();
    if (k0 + 32 < K) {
      gl16(Ag + k0 + 32, &Alds[cur ^ 1][w * 32][0]);
      gl16(Ag + k0 + 32 + 16 * K, &Alds[cur ^ 1][w * 32 + 16][0]);
      gl16(Bg + k0 + 32, &Blds[cur ^ 1][w * 16][0]);
      asm volatile("s_waitcnt vmcnt(3)" ::: "memory");
    } else {
      asm volatile("s_waitcnt vmcnt(0)" ::: "memory");
    }
    __builtin_amdgcn_sched_barrier(0);
    bf16x8 af[2], bfr[4];
#pragma unroll
    for (int i = 0; i < 2; ++i)
      af[i] = *reinterpret_cast<const bf16x8*>(&Alds[cur][w * 32 + i * 16 + lr][lg * 8]);
#pragma unroll
    for (int i = 0; i < 4; ++i)
      bfr[i] = *reinterpret_cast<const bf16x8*>(&Blds[cur][i * 16 + lr][lg * 8]);
#pragma unroll
    for (int mi = 0; mi < 2; ++mi)
#pragma unroll
      for (int ni = 0; ni < 4; ++ni)
        acc[mi][ni] = __builtin_amdgcn_mfma_f32_16x16x32_bf16(af[mi], bfr[ni], acc[mi][ni], 0, 0, 0);
    cur ^= 1;
  }

#pragma unroll
  for (int mi = 0; mi < 2; ++mi)
#pragma unroll
    for (int r = 0; r < 4; ++r) {
      const int row = m0 + w * 32 + mi * 16 + lg * 4 + r;
#pragma unroll
      for (int ni = 0; ni < 4; ++ni) {
        const int col = n0 + ni * 16 + lr;
        out[(size_t)row * ND + col] = acc[mi][ni][r] + bias[col];
      }
    }
}

// ---------------- fused masked flash attention (v7: v6 + XCD-chunked block mapping) --------
// grid (16, NH, NB) = 512 blocks x 8 waves, 128-row q-tiles, dbuf K/V via global_load_lds,
// counted vmcnt, defer-max. T1 remap: XCD x hosts 4 (b,h) panels (2MB K/V -> L2-resident);
// within XCD, g=j>>4 picks (b,h), t=j&15 picks qt with qt = (g&2)? t : 15-t so the co-resident
// pair (hid, hid+256 -> g+2) remains complementary in cost and heavy tiles dispatch first.
__global__ void __launch_bounds__(512, 4)
attn_fused(const u16* __restrict__ qb, const u16* __restrict__ kb, const u16* __restrict__ vtb,
           const u64* __restrict__ mb, u16* __restrict__ attnout) {
  __shared__ alignas(16) u16 Klds[2][64][64];   // [buf][k][d]  rows 128B, swizzled 16B units
  __shared__ alignas(16) u16 Vlds[2][64][64];   // [buf][d][k]
  __shared__ alignas(16) u16 Plds[8][16][64];   // per-wave P [q][k], swizzled 8B units
  const int t = threadIdx.x, w = t >> 6, lane = t & 63, lr = lane & 15, lg = lane >> 4;
  const int hid = (int)blockIdx.x + 16 * (int)blockIdx.y + 256 * (int)blockIdx.z;  // 0..511
  const int xcd = hid & 7, j = hid >> 3, g = j >> 4, tq = j & 15;
  const int bh = xcd * 4 + g;                   // 4 (b,h) panels per XCD
  const int b = bh >> 4, h = bh & 15;
  const int qt = (g & 2) ? tq : 15 - tq;        // complementary pairs, heavy-first
  const int qbase = qt * 128;
  const u16* __restrict__ qh = qb + (size_t)(b * NH + h) * NS * HD;
  const u16* __restrict__ kh = kb + (size_t)(b * NH + h) * NS * HD;
  const u16* __restrict__ vth = vtb + (size_t)(b * NH + h) * HD * NS;

  // staging: wave w stages rows w*8..w*8+7 of K and of V (one gl16 each).
  // LDS linear, global source pre-swizzled: 16B unit col' = col ^ (row&7); row&7 == srow.
  const int srow = lane >> 3;  // 0..7
  const int lcol = (lane & 7) ^ srow;
  const int sw = lr & 7;

  // Q fragments (B-operand of swapped QK^T): rows q = qbase + w*16 + lr
  const int qrow = qbase + w * 16 + lr;
  const bf16x8 qf0 = *reinterpret_cast<const bf16x8*>(qh + (size_t)qrow * HD + lg * 8);
  const bf16x8 qf1 = *reinterpret_cast<const bf16x8*>(qh + (size_t)qrow * HD + 32 + lg * 8);
  const u64* __restrict__ mrow = mb + (((size_t)b * NS + qrow) << 5);

  float m_s = -1e30f, l_s = 0.f;
  f32x4 oacc[4] = {};
  const int nt = 2 * qt + 2;  // causal: keys < qbase+128
  int cur = 0;

  // prologue: stage tile 0
  {
    const int row = w * 8 + srow;
    gl16(kh + (size_t)row * HD + lcol * 8, &Klds[0][w * 8][0]);
    gl16(vth + (size_t)row * NS + lcol * 8, &Vlds[0][w * 8][0]);
  }
  u64 mw = mrow[0];

  for (int kt = 0; kt < nt; ++kt) {
    __builtin_amdgcn_s_barrier();  // all waves done reading buf[cur^1]; no vmcnt drain
    if (kt + 1 < nt) {
      const int kb0n = (kt + 1) * 64;
      const int row = w * 8 + srow;
      gl16(kh + (size_t)(kb0n + row) * HD + lcol * 8, &Klds[cur ^ 1][w * 8][0]);
      gl16(vth + (size_t)row * NS + kb0n + lcol * 8, &Vlds[cur ^ 1][w * 8][0]);
      asm volatile("s_waitcnt vmcnt(2)" ::: "memory");  // buf[cur]'s 2 loads landed
    } else {
      asm volatile("s_waitcnt vmcnt(0)" ::: "memory");
    }
    __builtin_amdgcn_sched_barrier(0);
    const u64 mwn = (kt + 1 < nt) ? mrow[kt + 1] : 0ULL;

    const u16* Kb = &Klds[cur][0][0];
    const u16* Vb = &Vlds[cur][0][0];

    // S^T = K * Q^T : sacc[n][r] = S[q = qrow][k = kt*64 + n*16 + lg*4 + r] (pre-scaled)
    f32x4 sacc[4] = {};
    __builtin_amdgcn_s_setprio(1);
#pragma unroll
    for (int n = 0; n < 4; ++n) {
      const u16* kr = Kb + (n * 16 + lr) * 64;
      bf16x8 kf0 = *reinterpret_cast<const bf16x8*>(kr + ((lg ^ sw) << 3));
      bf16x8 kf1 = *reinterpret_cast<const bf16x8*>(kr + (((4 + lg) ^ sw) << 3));
      sacc[n] = __builtin_amdgcn_mfma_f32_16x16x32_bf16(kf0, qf0, sacc[n], 0, 0, 0);
      sacc[n] = __builtin_amdgcn_mfma_f32_16x16x32_bf16(kf1, qf1, sacc[n], 0, 0, 0);
    }
    __builtin_amdgcn_s_setprio(0);

    // mask (bit test) + tree row-max. masked -> -3e30 so exp underflows even vs m = -1e30.
    float pm[4][4];
    float mx4[4];
#pragma unroll
    for (int n = 0; n < 4; ++n) {
#pragma unroll
      for (int r = 0; r < 4; ++r) {
        const bool vis = (mw >> (n * 16 + lg * 4 + r)) & 1ULL;
        pm[n][r] = vis ? sacc[n][r] : -3e30f;
      }
      mx4[n] = fmaxf(fmaxf(pm[n][0], pm[n][1]), fmaxf(pm[n][2], pm[n][3]));
    }
    float mx = fmaxf(fmaxf(mx4[0], mx4[1]), fmaxf(mx4[2], mx4[3]));
    mx = fmaxf(mx, __shfl_xor(mx, 16));
    mx = fmaxf(mx, __shfl_xor(mx, 32));

    // defer-max: if no row grew past m+8, keep old max (skip rescale entirely)
    const bool skip = __all(mx <= m_s + 8.f);
    const float mn = skip ? m_s : fmaxf(m_s, mx);

    // exp + pack P to per-wave Plds (row q=lr, 4 consecutive k per b64 write, swizzled)
    float rs = 0.f;
#pragma unroll
    for (int n = 0; n < 4; ++n) {
      const float e0 = __expf(pm[n][0] - mn);
      const float e1 = __expf(pm[n][1] - mn);
      const float e2 = __expf(pm[n][2] - mn);
      const float e3 = __expf(pm[n][3] - mn);
      rs += (e0 + e1) + (e2 + e3);
      uint2 pk;
      pk.x = (unsigned)bfbits(e0) | ((unsigned)bfbits(e1) << 16);
      pk.y = (unsigned)bfbits(e2) | ((unsigned)bfbits(e3) << 16);
      *reinterpret_cast<uint2*>(&Plds[w][lr][(((n << 2) + lg) ^ (lr & 14)) << 2]) = pk;
    }
    rs += __shfl_xor(rs, 16);
    rs += __shfl_xor(rs, 32);

    if (skip) {
      l_s += rs;
    } else {
      const float sf = __expf(m_s - mn);
      m_s = mn;
      l_s = l_s * sf + rs;
      float sfr[4];
#pragma unroll
      for (int r = 0; r < 4; ++r) sfr[r] = __shfl(sf, lg * 4 + r);
#pragma unroll
      for (int nd = 0; nd < 4; ++nd)
#pragma unroll
        for (int r = 0; r < 4; ++r) oacc[nd][r] *= sfr[r];
    }

    // PV: O[q][d] += P[q][k] * V^T[d][k]
    const bf16x8 pf0 = *reinterpret_cast<const bf16x8*>(&Plds[w][lr][((2 * lg) ^ (lr & 14)) << 2]);
    const bf16x8 pf1 = *reinterpret_cast<const bf16x8*>(&Plds[w][lr][((8 + 2 * lg) ^ (lr & 14)) << 2]);
    __builtin_amdgcn_s_setprio(1);
#pragma unroll
    for (int nd = 0; nd < 4; ++nd) {
      const u16* vr = Vb + (nd * 16 + lr) * 64;
      bf16x8 vf0 = *reinterpret_cast<const bf16x8*>(vr + ((lg ^ sw) << 3));
      bf16x8 vf1 = *reinterpret_cast<const bf16x8*>(vr + (((4 + lg) ^ sw) << 3));
      oacc[nd] = __builtin_amdgcn_mfma_f32_16x16x32_bf16(pf0, vf0, oacc[nd], 0, 0, 0);
      oacc[nd] = __builtin_amdgcn_mfma_f32_16x16x32_bf16(pf1, vf1, oacc[nd], 0, 0, 0);
    }
    __builtin_amdgcn_s_setprio(0);

    mw = mwn;
    cur ^= 1;
  }

  float il[4];
#pragma unroll
  for (int r = 0; r < 4; ++r) il[r] = 1.f / __shfl(l_s, lg * 4 + r);
#pragma unroll
  for (int nd = 0; nd < 4; ++nd)
#pragma unroll
    for (int r = 0; r < 4; ++r) {
      const int i = qbase + w * 16 + lg * 4 + r;
      attnout[(size_t)(b * NS + i) * ND + h * HD + nd * 16 + lr] = bfbits(oacc[nd][r] * il[r]);
    }
}

// ---------------- launch ----------------
extern "C" void kernel_launch(void* const* d_in, const int* in_sizes, int n_in,
                              void* d_out, int out_size, void* d_ws, size_t ws_size,
                              hipStream_t stream) {
  const float* x = (const float*)d_in[0];
  const int* bar = (const int*)d_in[1];
  const int* inst = (const int*)d_in[2];
  const int* lidx = (const int*)d_in[3];
  const float* Wq = (const float*)d_in[4];
  const float* bq = (const float*)d_in[5];
  const float* Wk = (const float*)d_in[6];
  const float* bk = (const float*)d_in[7];
  const float* Wv = (const float*)d_in[8];
  const float* bv = (const float*)d_in[9];
  const float* Wo = (const float*)d_in[10];
  const float* bo = (const float*)d_in[11];
  float* out = (float*)d_out;

  char* ws = (char*)d_ws;
  constexpr size_t XB = (size_t)NB * NS * ND * 2;   // 8 MB bf16 token-major buffer
  constexpr size_t WT = (size_t)ND * ND * 2;        // 2 MB
  u16* xb   = (u16*)(ws);
  u16* WqT  = (u16*)(ws + XB);                      // WqT|WkT|WvT contiguous = [3072][1024]
  u16* WkT  = (u16*)(ws + XB + 1 * WT);
  u16* WvT  = (u16*)(ws + XB + 2 * WT);
  u16* WoT  = (u16*)(ws + XB + 3 * WT);
  u16* qbuf = (u16*)(ws + XB + 4 * WT);
  u16* kbuf = (u16*)(ws + XB + 4 * WT + XB);
  u16* vtbuf= (u16*)(ws + XB + 4 * WT + 2 * XB);
  float* cost = (float*)(ws + XB + 4 * WT + 3 * XB);
  float* sint = cost + NS * 32;
  u64* maskbuf = (u64*)(ws + XB + 4 * WT + 3 * XB + (size_t)NS * 32 * 4 * 2);  // 1 MB
  u16* attnout = xb;  // alias: xb is dead after the QKV GEMM (stream-ordered)

  prep_weight4<<<dim3(32, 32, 4), dim3(32, 8), 0, stream>>>(Wq, Wk, Wv, Wo, WqT, WkT, WvT, WoT);
  convert_x_rope<<<(NB * NS * ND / 4) / 256 + (NS * 32) / 256, 256, 0, stream>>>(x, xb, cost, sint);
  build_mask<<<dim3(NB * NS / 4), 256, 0, stream>>>(bar, inst, lidx, maskbuf);

  gemm_qkv<<<dim3(24, 32), 256, 0, stream>>>(xb, WqT, bq, bk, bv, qbuf, kbuf, vtbuf, cost, sint);

  attn_fused<<<dim3(16, NH, NB), 512, 0, stream>>>(qbuf, kbuf, vtbuf, maskbuf, attnout);

  gemm_out<<<dim3(16, 32), 256, 0, stream>>>(attnout, WoT, bo, out);
}